// Round 14
// baseline (264.491 us; speedup 1.0000x reference)
//
#include <hip/hip_runtime.h>
#include <math.h>

#define Bb 256
#define Tt 1024
#define Ll 128

typedef float v2f __attribute__((ext_vector_type(2)));

// ---------------- exp(trans) transpose precompute ----------------
// expT[j*128 + i] = exp(trans[i*128 + j])
__global__ __launch_bounds__(256) void crf_expT_kernel(
    const float* __restrict__ trans, float* __restrict__ expT)
{
    int idx = blockIdx.x * 256 + threadIdx.x;   // idx = j*128 + i
    if (idx < Ll * Ll) {
        int jj = idx >> 7;
        int ii = idx & (Ll - 1);
        expT[idx] = __expf(trans[ii * Ll + jj]);
    }
}

// ---------------- numerator kernel ----------------
__global__ __launch_bounds__(256) void crf_num_kernel(
    const float* __restrict__ h, const int* __restrict__ labels,
    const float* __restrict__ mask, const float* __restrict__ trans,
    const float* __restrict__ start_trans, const float* __restrict__ end_trans,
    float* __restrict__ num_out)
{
    const int b = blockIdx.x;
    const int tid = threadIdx.x;
    const int* lab = labels + b * Tt;
    const float* mk = mask + b * Tt;
    const float* hb = h + (size_t)b * Tt * Ll;

    float acc = 0.f;
    float msum = 0.f;
    for (int t = tid; t < Tt; t += 256) {
        int lt = lab[t];
        float mt = mk[t];
        msum += mt;
        if (t < Tt - 1) {
            int lt1 = lab[t + 1];
            acc += hb[t * Ll + lt] * mt + trans[lt * Ll + lt1] * mk[t + 1];
        }
    }
    for (int off = 32; off; off >>= 1) {
        acc  += __shfl_down(acc, off, 64);
        msum += __shfl_down(msum, off, 64);
    }
    __shared__ float racc[4], rmsum[4];
    const int wave = tid >> 6;
    if ((tid & 63) == 0) { racc[wave] = acc; rmsum[wave] = msum; }
    __syncthreads();
    if (tid == 0) {
        float a = racc[0] + racc[1] + racc[2] + racc[3];
        float m = rmsum[0] + rmsum[1] + rmsum[2] + rmsum[3];
        int last_idx = (int)(m + 0.5f) - 1;
        if (last_idx < 0) last_idx = 0;
        if (last_idx > Tt - 1) last_idx = Tt - 1;
        int last_lab = lab[last_idx];
        float num = a + start_trans[lab[0]];
        num += hb[(Tt - 1) * Ll + last_lab] * mk[Tt - 1];
        num += end_trans[last_lab];
        num_out[b] = num;
    }
}

// ---------------- denominator (forward scan) kernel ----------------
// R11 structure restored (4 waves/256 thr, 4 cols x 16 i per thread, padded
// p, slot-refill x4, shift update every 4th step, mask in LDS, m201 barrier).
// R12's 8-wave retile REVERTED: per-thread overhead is tiling-invariant, so
// 2 waves/SIMD doubled issue (VALU 292->465 cy/step/SIMD) for -20% per-wave.
// Two issue cuts this round (algebra identical; absmax 0.0 since R9):
//  * plain v2f mul/add (R11's asm PKFMA measured +20cy of copies vs R10)
//  * MERGED butterfly reduce: mirror level (4dpp+4add) then cndmask-merge
//    xor1/xor2 levels fold acc-selection into the butterfly: 20 instr vs 27,
//    shorter dep chain. Lane s ends holding the full sum of col jbase+(s&3).
__global__ __launch_bounds__(256)
__attribute__((amdgpu_waves_per_eu(1, 1)))
void crf_den_kernel(
    const float* __restrict__ h, const float* __restrict__ mask,
    const float* __restrict__ expT, const float* __restrict__ start_trans,
    const float* __restrict__ end_trans, const float* __restrict__ num_in,
    float* __restrict__ out)
{
    __shared__ float p_lds[2][160];      // padded: addr(i) = i + (i>>4)*4
    __shared__ float mk_lds[Tt];         // staged mask row (4KB)
    __shared__ float redm[4], reds[4];

    const int b = blockIdx.x;
    const int tid = threadIdx.x;
    const int wave = tid >> 6;
    const int lane = tid & 63;
    const int jgrp = lane >> 3;                    // 8 column-groups per wave
    const int isl  = lane & 7;                     // i-slice 0..7 (16 i each)
    const int jbase = (wave << 5) + (jgrp << 2);   // 4 columns per thread
    const int wcol  = jbase + (isl & 3);           // column this lane writes
    const bool writer = (isl < 4);
    const int waddr = wcol + ((wcol >> 4) << 2);
    const bool lb0 = (lane & 1) != 0;              // lane bit0 (acc-merge sel)
    const bool lb1 = (lane & 2) != 0;              // lane bit1

    const float* hb = h + (size_t)b * Tt * Ll;
    const float* mk = mask + b * Tt;

    // stage mask row into LDS, vectorized (256 threads x float4 = 1024)
    ((float4*)mk_lds)[tid] = ((const float4*)mk)[tid];

    // E fragment: cols jbase+0..3, i in [isl*16, isl*16+16) -> 32 v2f regs
    const v2f* EAp = (const v2f*)(expT + (jbase + 0) * Ll + (isl << 4));
    const v2f* EBp = (const v2f*)(expT + (jbase + 1) * Ll + (isl << 4));
    const v2f* ECp = (const v2f*)(expT + (jbase + 2) * Ll + (isl << 4));
    const v2f* EDp = (const v2f*)(expT + (jbase + 3) * Ll + (isl << 4));
    v2f EA0=EAp[0],EA1=EAp[1],EA2=EAp[2],EA3=EAp[3],EA4=EAp[4],EA5=EAp[5],EA6=EAp[6],EA7=EAp[7];
    v2f EB0=EBp[0],EB1=EBp[1],EB2=EBp[2],EB3=EBp[3],EB4=EBp[4],EB5=EBp[5],EB6=EBp[6],EB7=EBp[7];
    v2f EC0=ECp[0],EC1=ECp[1],EC2=ECp[2],EC3=ECp[3],EC4=ECp[4],EC5=ECp[5],EC6=ECp[6],EC7=ECp[7];
    v2f ED0=EDp[0],ED1=EDp[1],ED2=EDp[2],ED3=EDp[3],ED4=EDp[4],ED5=EDp[5],ED6=EDp[6],ED7=EDp[7];

    // bootstrap t = 0: shift S0 = score_0[0] + 16, computed uniformly
    float S = start_trans[0] + hb[0] + 16.0f;
    float score0 = start_trans[wcol] + hb[wcol];
    float pw = __expf(score0 - S);
    if (writer) p_lds[0][waddr] = pw;

    // h/mask slots (slot r holds data for time t with t&3 == r)
    float h1 = hb[1 * Ll + wcol], m1 = mk[1];
    float h2 = hb[2 * Ll + wcol], m2 = mk[2];
    float h3 = hb[3 * Ll + wcol], m3 = mk[3];
    float h0 = hb[4 * Ll + wcol], m0 = mk[4];
    __syncthreads();

    float ex1 = __expf(h1) * m1, om1 = 1.f - m1;
    float ex0, om0, ex2, om2, ex3, om3;

    // DPP cross-lane value; old=0, bound_ctrl=true (foldable to *_dpp ALU)
#define DPPA(x, ctrl) __int_as_float(__builtin_amdgcn_update_dpp( \
        0, __float_as_int(x), ctrl, 0xF, 0xF, true))

    // BODY: one scan step. RBUF = buffer read (write RBUF^1). UPD = shift
    // update step. EXc/OMc = this step's coeffs (prepared last body).
    // EXn/OMn prepared here from slot (HN,MN) for the NEXT body.
    // (HR,MR) refilled with time TR (consumed 3 bodies later; h from global
    // [vmcnt, never drained], mask from LDS broadcast [lgkm, same-step ok]).
    // Reduce: mirror(0x141) sums slice pairs (s,7-s); then xor1(0xB1) and
    // xor2(0x4E) levels MERGE accumulators via cndmask-pair: lane s ends
    // with the full 8-slice sum of acc (s&3) = col jbase+(s&3) = wcol.
#define BODY(RBUF, UPD, EXc, OMc, HN, MN, EXn, OMn, HR, MR, TR) {      \
    const float4* pp = (const float4*)(&p_lds[RBUF][isl * 20]);        \
    float4 Q0 = pp[0], Q1 = pp[1], Q2 = pp[2], Q3 = pp[3];             \
    float pz = 0.f;                                                    \
    if (UPD) pz = p_lds[RBUF][0];                                      \
    HR = hb[(TR) * Ll + wcol];                                         \
    MR = mk_lds[(TR)];                                                 \
    v2f q00 = {Q0.x,Q0.y}, q01 = {Q0.z,Q0.w};                          \
    v2f q10 = {Q1.x,Q1.y}, q11 = {Q1.z,Q1.w};                          \
    v2f q20 = {Q2.x,Q2.y}, q21 = {Q2.z,Q2.w};                          \
    v2f q30 = {Q3.x,Q3.y}, q31 = {Q3.z,Q3.w};                          \
    v2f A0 = q00*EA0; A0 = q01*EA1 + A0; A0 = q10*EA2 + A0;            \
    A0 = q11*EA3 + A0; A0 = q20*EA4 + A0; A0 = q21*EA5 + A0;           \
    A0 = q30*EA6 + A0; A0 = q31*EA7 + A0;                              \
    v2f A1 = q00*EB0; A1 = q01*EB1 + A1; A1 = q10*EB2 + A1;            \
    A1 = q11*EB3 + A1; A1 = q20*EB4 + A1; A1 = q21*EB5 + A1;           \
    A1 = q30*EB6 + A1; A1 = q31*EB7 + A1;                              \
    v2f A2 = q00*EC0; A2 = q01*EC1 + A2; A2 = q10*EC2 + A2;            \
    A2 = q11*EC3 + A2; A2 = q20*EC4 + A2; A2 = q21*EC5 + A2;           \
    A2 = q30*EC6 + A2; A2 = q31*EC7 + A2;                              \
    v2f A3 = q00*ED0; A3 = q01*ED1 + A3; A3 = q10*ED2 + A3;            \
    A3 = q11*ED3 + A3; A3 = q20*ED4 + A3; A3 = q21*ED5 + A3;           \
    A3 = q30*ED6 + A3; A3 = q31*ED7 + A3;                              \
    float a0 = A0.x + A0.y, a1 = A1.x + A1.y;                          \
    float a2 = A2.x + A2.y, a3 = A3.x + A3.y;                          \
    a0 += DPPA(a0, 0x141); a1 += DPPA(a1, 0x141);                      \
    a2 += DPPA(a2, 0x141); a3 += DPPA(a3, 0x141);                      \
    float u01 = lb0 ? a1 : a0, v01 = lb0 ? a0 : a1;                    \
    float b01 = u01 + DPPA(v01, 0xB1);                                 \
    float u23 = lb0 ? a3 : a2, v23 = lb0 ? a2 : a3;                    \
    float b23 = u23 + DPPA(v23, 0xB1);                                 \
    float uf = lb1 ? b23 : b01, vf = lb1 ? b01 : b23;                  \
    float acc = uf + DPPA(vf, 0x4E);                                   \
    float c1 = EXc, c0 = pw * OMc;                                     \
    if (UPD) { float ed = __fdividef(1.12535175e-7f, pz);              \
               c1 *= ed; c0 *= ed; S += __logf(pz) + 16.0f; }          \
    float pn = fmaf(acc, c1, c0);                                      \
    if (writer) p_lds[(RBUF) ^ 1][waddr] = pn;                         \
    EXn = __expf(HN) * MN; OMn = 1.f - MN;                             \
    pw = pn;                                                           \
    __builtin_amdgcn_sched_barrier(0);                                 \
    asm volatile("s_waitcnt lgkmcnt(0)");                              \
    __builtin_amdgcn_s_barrier();                                      \
    __builtin_amdgcn_sched_barrier(0);                                 \
}

    // pre-loop bodies: t = 1, 2, 3 (regular; S unchanged)
    BODY(0, 0, ex1, om1, h2, m2, ex2, om2, h1, m1, 5)
    BODY(1, 0, ex2, om2, h3, m3, ex3, om3, h2, m2, 6)
    BODY(0, 0, ex3, om3, h0, m0, ex0, om0, h3, m3, 7)

    // main loop: k = 1..254, t = 4k (update), 4k+1, 4k+2, 4k+3.
    // TR = t+4 <= 1023 throughout -> no clamp arithmetic in the hot loop.
    for (int k = 1; k < 255; ++k) {
        int t4 = k << 2;
        BODY(1, 1, ex0, om0, h1, m1, ex1, om1, h0, m0, t4 + 4)
        BODY(0, 0, ex1, om1, h2, m2, ex2, om2, h1, m1, t4 + 5)
        BODY(1, 0, ex2, om2, h3, m3, ex3, om3, h2, m2, t4 + 6)
        BODY(0, 0, ex3, om3, h0, m0, ex0, om0, h3, m3, t4 + 7)
    }
    // tail k = 255: t = 1020..1023; refills are dummies (never consumed)
    BODY(1, 1, ex0, om0, h1, m1, ex1, om1, h0, m0, Tt - 1)
    BODY(0, 0, ex1, om1, h2, m2, ex2, om2, h1, m1, Tt - 1)
    BODY(1, 0, ex2, om2, h3, m3, ex3, om3, h2, m2, Tt - 1)
    BODY(0, 0, ex3, om3, h0, m0, ex0, om0, h3, m3, Tt - 1)
#undef BODY
#undef DPPA

    // ---- final logsumexp: score_j = log(p_T[j]) + S ----
    float v = __logf(pw) + S + end_trans[wcol];
    float mval = writer ? v : -1e30f;
    #pragma unroll
    for (int off = 32; off; off >>= 1) mval = fmaxf(mval, __shfl_xor(mval, off, 64));
    if (lane == 0) redm[wave] = mval;
    __syncthreads();
    float M = fmaxf(fmaxf(redm[0], redm[1]), fmaxf(redm[2], redm[3]));
    float e = writer ? __expf(v - M) : 0.f;
    #pragma unroll
    for (int off = 32; off; off >>= 1) e += __shfl_xor(e, off, 64);
    if (lane == 0) reds[wave] = e;
    __syncthreads();
    if (tid == 0) {
        float den = M + __logf(reds[0] + reds[1] + reds[2] + reds[3]);
        out[b] = num_in[b] - den;
    }
}

extern "C" void kernel_launch(void* const* d_in, const int* in_sizes, int n_in,
                              void* d_out, int out_size, void* d_ws, size_t ws_size,
                              hipStream_t stream) {
    const float* h           = (const float*)d_in[0];
    const int*   labels      = (const int*)d_in[1];
    const float* mask        = (const float*)d_in[2];
    const float* trans       = (const float*)d_in[3];
    const float* start_trans = (const float*)d_in[4];
    const float* end_trans   = (const float*)d_in[5];
    float* out    = (float*)d_out;
    float* num_ws = (float*)d_ws;                 // [0, 256)         num results
    float* expT   = (float*)d_ws + 256;           // [256, 256+16384) exp(trans)^T

    crf_expT_kernel<<<(Ll * Ll + 255) / 256, 256, 0, stream>>>(trans, expT);
    crf_num_kernel<<<Bb, 256, 0, stream>>>(h, labels, mask, trans, start_trans, end_trans, num_ws);
    crf_den_kernel<<<Bb, 256, 0, stream>>>(h, mask, expT, start_trans, end_trans, num_ws, out);
}

// Round 15
// 263.694 us; speedup vs baseline: 1.0030x; 1.0030x over previous
//
#include <hip/hip_runtime.h>
#include <math.h>

#define Bb 256
#define Tt 1024
#define Ll 128

typedef float v2f __attribute__((ext_vector_type(2)));

// ---------------- exp(trans) transpose precompute ----------------
// expT[j*128 + i] = exp(trans[i*128 + j])
__global__ __launch_bounds__(256) void crf_expT_kernel(
    const float* __restrict__ trans, float* __restrict__ expT)
{
    int idx = blockIdx.x * 256 + threadIdx.x;   // idx = j*128 + i
    if (idx < Ll * Ll) {
        int jj = idx >> 7;
        int ii = idx & (Ll - 1);
        expT[idx] = __expf(trans[ii * Ll + jj]);
    }
}

// ---------------- numerator kernel ----------------
__global__ __launch_bounds__(256) void crf_num_kernel(
    const float* __restrict__ h, const int* __restrict__ labels,
    const float* __restrict__ mask, const float* __restrict__ trans,
    const float* __restrict__ start_trans, const float* __restrict__ end_trans,
    float* __restrict__ num_out)
{
    const int b = blockIdx.x;
    const int tid = threadIdx.x;
    const int* lab = labels + b * Tt;
    const float* mk = mask + b * Tt;
    const float* hb = h + (size_t)b * Tt * Ll;

    float acc = 0.f;
    float msum = 0.f;
    for (int t = tid; t < Tt; t += 256) {
        int lt = lab[t];
        float mt = mk[t];
        msum += mt;
        if (t < Tt - 1) {
            int lt1 = lab[t + 1];
            acc += hb[t * Ll + lt] * mt + trans[lt * Ll + lt1] * mk[t + 1];
        }
    }
    for (int off = 32; off; off >>= 1) {
        acc  += __shfl_down(acc, off, 64);
        msum += __shfl_down(msum, off, 64);
    }
    __shared__ float racc[4], rmsum[4];
    const int wave = tid >> 6;
    if ((tid & 63) == 0) { racc[wave] = acc; rmsum[wave] = msum; }
    __syncthreads();
    if (tid == 0) {
        float a = racc[0] + racc[1] + racc[2] + racc[3];
        float m = rmsum[0] + rmsum[1] + rmsum[2] + rmsum[3];
        int last_idx = (int)(m + 0.5f) - 1;
        if (last_idx < 0) last_idx = 0;
        if (last_idx > Tt - 1) last_idx = Tt - 1;
        int last_lab = lab[last_idx];
        float num = a + start_trans[lab[0]];
        num += hb[(Tt - 1) * Ll + last_lab] * mk[Tt - 1];
        num += end_trans[last_lab];
        num_out[b] = num;
    }
}

// ---------------- denominator (forward scan) kernel ----------------
// R11 structure restored (4 waves/256 thr, 4 cols x 16 i per thread, padded
// p, slot-refill x4, shift update every 4th step, mask in LDS, m201 barrier).
// R12's 8-wave retile REVERTED: per-thread overhead is tiling-invariant, so
// 2 waves/SIMD doubled issue (VALU 292->465 cy/step/SIMD) for -20% per-wave.
// Two issue cuts this round (algebra identical; absmax 0.0 since R9):
//  * plain v2f mul/add (R11's asm PKFMA measured +20cy of copies vs R10)
//  * MERGED butterfly reduce: mirror level (4dpp+4add) then cndmask-merge
//    xor1/xor2 levels fold acc-selection into the butterfly: 20 instr vs 27,
//    shorter dep chain. Lane s ends holding the full sum of col jbase+(s&3).
__global__ __launch_bounds__(256)
__attribute__((amdgpu_waves_per_eu(1, 1)))
void crf_den_kernel(
    const float* __restrict__ h, const float* __restrict__ mask,
    const float* __restrict__ expT, const float* __restrict__ start_trans,
    const float* __restrict__ end_trans, const float* __restrict__ num_in,
    float* __restrict__ out)
{
    __shared__ float p_lds[2][160];      // padded: addr(i) = i + (i>>4)*4
    __shared__ float mk_lds[Tt];         // staged mask row (4KB)
    __shared__ float redm[4], reds[4];

    const int b = blockIdx.x;
    const int tid = threadIdx.x;
    const int wave = tid >> 6;
    const int lane = tid & 63;
    const int jgrp = lane >> 3;                    // 8 column-groups per wave
    const int isl  = lane & 7;                     // i-slice 0..7 (16 i each)
    const int jbase = (wave << 5) + (jgrp << 2);   // 4 columns per thread
    const int wcol  = jbase + (isl & 3);           // column this lane writes
    const bool writer = (isl < 4);
    const int waddr = wcol + ((wcol >> 4) << 2);
    const bool lb0 = (lane & 1) != 0;              // lane bit0 (acc-merge sel)
    const bool lb1 = (lane & 2) != 0;              // lane bit1

    const float* hb = h + (size_t)b * Tt * Ll;
    const float* mk = mask + b * Tt;

    // stage mask row into LDS, vectorized (256 threads x float4 = 1024)
    ((float4*)mk_lds)[tid] = ((const float4*)mk)[tid];

    // E fragment: cols jbase+0..3, i in [isl*16, isl*16+16) -> 32 v2f regs
    const v2f* EAp = (const v2f*)(expT + (jbase + 0) * Ll + (isl << 4));
    const v2f* EBp = (const v2f*)(expT + (jbase + 1) * Ll + (isl << 4));
    const v2f* ECp = (const v2f*)(expT + (jbase + 2) * Ll + (isl << 4));
    const v2f* EDp = (const v2f*)(expT + (jbase + 3) * Ll + (isl << 4));
    v2f EA0=EAp[0],EA1=EAp[1],EA2=EAp[2],EA3=EAp[3],EA4=EAp[4],EA5=EAp[5],EA6=EAp[6],EA7=EAp[7];
    v2f EB0=EBp[0],EB1=EBp[1],EB2=EBp[2],EB3=EBp[3],EB4=EBp[4],EB5=EBp[5],EB6=EBp[6],EB7=EBp[7];
    v2f EC0=ECp[0],EC1=ECp[1],EC2=ECp[2],EC3=ECp[3],EC4=ECp[4],EC5=ECp[5],EC6=ECp[6],EC7=ECp[7];
    v2f ED0=EDp[0],ED1=EDp[1],ED2=EDp[2],ED3=EDp[3],ED4=EDp[4],ED5=EDp[5],ED6=EDp[6],ED7=EDp[7];

    // bootstrap t = 0: shift S0 = score_0[0] + 16, computed uniformly
    float S = start_trans[0] + hb[0] + 16.0f;
    float score0 = start_trans[wcol] + hb[wcol];
    float pw = __expf(score0 - S);
    if (writer) p_lds[0][waddr] = pw;

    // h/mask slots (slot r holds data for time t with t&3 == r)
    float h1 = hb[1 * Ll + wcol], m1 = mk[1];
    float h2 = hb[2 * Ll + wcol], m2 = mk[2];
    float h3 = hb[3 * Ll + wcol], m3 = mk[3];
    float h0 = hb[4 * Ll + wcol], m0 = mk[4];
    __syncthreads();

    float ex1 = __expf(h1) * m1, om1 = 1.f - m1;
    float ex0, om0, ex2, om2, ex3, om3;

    // DPP cross-lane value; old=0, bound_ctrl=true (foldable to *_dpp ALU)
#define DPPA(x, ctrl) __int_as_float(__builtin_amdgcn_update_dpp( \
        0, __float_as_int(x), ctrl, 0xF, 0xF, true))

    // BODY: one scan step. RBUF = buffer read (write RBUF^1). UPD = shift
    // update step. EXc/OMc = this step's coeffs (prepared last body).
    // EXn/OMn prepared here from slot (HN,MN) for the NEXT body.
    // (HR,MR) refilled with time TR (consumed 3 bodies later; h from global
    // [vmcnt, never drained], mask from LDS broadcast [lgkm, same-step ok]).
    // Reduce: mirror(0x141) sums slice pairs (s,7-s); then xor1(0xB1) and
    // xor2(0x4E) levels MERGE accumulators via cndmask-pair: lane s ends
    // with the full 8-slice sum of acc (s&3) = col jbase+(s&3) = wcol.
#define BODY(RBUF, UPD, EXc, OMc, HN, MN, EXn, OMn, HR, MR, TR) {      \
    const float4* pp = (const float4*)(&p_lds[RBUF][isl * 20]);        \
    float4 Q0 = pp[0], Q1 = pp[1], Q2 = pp[2], Q3 = pp[3];             \
    float pz = 0.f;                                                    \
    if (UPD) pz = p_lds[RBUF][0];                                      \
    HR = hb[(TR) * Ll + wcol];                                         \
    MR = mk_lds[(TR)];                                                 \
    v2f q00 = {Q0.x,Q0.y}, q01 = {Q0.z,Q0.w};                          \
    v2f q10 = {Q1.x,Q1.y}, q11 = {Q1.z,Q1.w};                          \
    v2f q20 = {Q2.x,Q2.y}, q21 = {Q2.z,Q2.w};                          \
    v2f q30 = {Q3.x,Q3.y}, q31 = {Q3.z,Q3.w};                          \
    v2f A0 = q00*EA0; A0 = q01*EA1 + A0; A0 = q10*EA2 + A0;            \
    A0 = q11*EA3 + A0; A0 = q20*EA4 + A0; A0 = q21*EA5 + A0;           \
    A0 = q30*EA6 + A0; A0 = q31*EA7 + A0;                              \
    v2f A1 = q00*EB0; A1 = q01*EB1 + A1; A1 = q10*EB2 + A1;            \
    A1 = q11*EB3 + A1; A1 = q20*EB4 + A1; A1 = q21*EB5 + A1;           \
    A1 = q30*EB6 + A1; A1 = q31*EB7 + A1;                              \
    v2f A2 = q00*EC0; A2 = q01*EC1 + A2; A2 = q10*EC2 + A2;            \
    A2 = q11*EC3 + A2; A2 = q20*EC4 + A2; A2 = q21*EC5 + A2;           \
    A2 = q30*EC6 + A2; A2 = q31*EC7 + A2;                              \
    v2f A3 = q00*ED0; A3 = q01*ED1 + A3; A3 = q10*ED2 + A3;            \
    A3 = q11*ED3 + A3; A3 = q20*ED4 + A3; A3 = q21*ED5 + A3;           \
    A3 = q30*ED6 + A3; A3 = q31*ED7 + A3;                              \
    float a0 = A0.x + A0.y, a1 = A1.x + A1.y;                          \
    float a2 = A2.x + A2.y, a3 = A3.x + A3.y;                          \
    a0 += DPPA(a0, 0x141); a1 += DPPA(a1, 0x141);                      \
    a2 += DPPA(a2, 0x141); a3 += DPPA(a3, 0x141);                      \
    float u01 = lb0 ? a1 : a0, v01 = lb0 ? a0 : a1;                    \
    float b01 = u01 + DPPA(v01, 0xB1);                                 \
    float u23 = lb0 ? a3 : a2, v23 = lb0 ? a2 : a3;                    \
    float b23 = u23 + DPPA(v23, 0xB1);                                 \
    float uf = lb1 ? b23 : b01, vf = lb1 ? b01 : b23;                  \
    float acc = uf + DPPA(vf, 0x4E);                                   \
    float c1 = EXc, c0 = pw * OMc;                                     \
    if (UPD) { float ed = __fdividef(1.12535175e-7f, pz);              \
               c1 *= ed; c0 *= ed; S += __logf(pz) + 16.0f; }          \
    float pn = fmaf(acc, c1, c0);                                      \
    if (writer) p_lds[(RBUF) ^ 1][waddr] = pn;                         \
    EXn = __expf(HN) * MN; OMn = 1.f - MN;                             \
    pw = pn;                                                           \
    __builtin_amdgcn_sched_barrier(0);                                 \
    asm volatile("s_waitcnt lgkmcnt(0)");                              \
    __builtin_amdgcn_s_barrier();                                      \
    __builtin_amdgcn_sched_barrier(0);                                 \
}

    // pre-loop bodies: t = 1, 2, 3 (regular; S unchanged)
    BODY(0, 0, ex1, om1, h2, m2, ex2, om2, h1, m1, 5)
    BODY(1, 0, ex2, om2, h3, m3, ex3, om3, h2, m2, 6)
    BODY(0, 0, ex3, om3, h0, m0, ex0, om0, h3, m3, 7)

    // main loop: k = 1..254, t = 4k (update), 4k+1, 4k+2, 4k+3.
    // TR = t+4 <= 1023 throughout -> no clamp arithmetic in the hot loop.
    for (int k = 1; k < 255; ++k) {
        int t4 = k << 2;
        BODY(1, 1, ex0, om0, h1, m1, ex1, om1, h0, m0, t4 + 4)
        BODY(0, 0, ex1, om1, h2, m2, ex2, om2, h1, m1, t4 + 5)
        BODY(1, 0, ex2, om2, h3, m3, ex3, om3, h2, m2, t4 + 6)
        BODY(0, 0, ex3, om3, h0, m0, ex0, om0, h3, m3, t4 + 7)
    }
    // tail k = 255: t = 1020..1023; refills are dummies (never consumed)
    BODY(1, 1, ex0, om0, h1, m1, ex1, om1, h0, m0, Tt - 1)
    BODY(0, 0, ex1, om1, h2, m2, ex2, om2, h1, m1, Tt - 1)
    BODY(1, 0, ex2, om2, h3, m3, ex3, om3, h2, m2, Tt - 1)
    BODY(0, 0, ex3, om3, h0, m0, ex0, om0, h3, m3, Tt - 1)
#undef BODY
#undef DPPA

    // ---- final logsumexp: score_j = log(p_T[j]) + S ----
    float v = __logf(pw) + S + end_trans[wcol];
    float mval = writer ? v : -1e30f;
    #pragma unroll
    for (int off = 32; off; off >>= 1) mval = fmaxf(mval, __shfl_xor(mval, off, 64));
    if (lane == 0) redm[wave] = mval;
    __syncthreads();
    float M = fmaxf(fmaxf(redm[0], redm[1]), fmaxf(redm[2], redm[3]));
    float e = writer ? __expf(v - M) : 0.f;
    #pragma unroll
    for (int off = 32; off; off >>= 1) e += __shfl_xor(e, off, 64);
    if (lane == 0) reds[wave] = e;
    __syncthreads();
    if (tid == 0) {
        float den = M + __logf(reds[0] + reds[1] + reds[2] + reds[3]);
        out[b] = num_in[b] - den;
    }
}

extern "C" void kernel_launch(void* const* d_in, const int* in_sizes, int n_in,
                              void* d_out, int out_size, void* d_ws, size_t ws_size,
                              hipStream_t stream) {
    const float* h           = (const float*)d_in[0];
    const int*   labels      = (const int*)d_in[1];
    const float* mask        = (const float*)d_in[2];
    const float* trans       = (const float*)d_in[3];
    const float* start_trans = (const float*)d_in[4];
    const float* end_trans   = (const float*)d_in[5];
    float* out    = (float*)d_out;
    float* num_ws = (float*)d_ws;                 // [0, 256)         num results
    float* expT   = (float*)d_ws + 256;           // [256, 256+16384) exp(trans)^T

    crf_expT_kernel<<<(Ll * Ll + 255) / 256, 256, 0, stream>>>(trans, expT);
    crf_num_kernel<<<Bb, 256, 0, stream>>>(h, labels, mask, trans, start_trans, end_trans, num_ws);
    crf_den_kernel<<<Bb, 256, 0, stream>>>(h, mask, expT, start_trans, end_trans, num_ws, out);
}

// Round 16
// 247.787 us; speedup vs baseline: 1.0674x; 1.0642x over previous
//
#include <hip/hip_runtime.h>
#include <math.h>

#define Bb 256
#define Tt 1024
#define Ll 128

typedef float v2f __attribute__((ext_vector_type(2)));

__device__ __forceinline__ v2f ev2(float a, float b) { v2f r; r.x = a; r.y = b; return r; }

// ---------------- fully fused CRF kernel ----------------
// One launch, grid 256 (1 block per batch), 256 threads (4 waves).
// Scan structure = R15 exactly (4 cols x 16 i per thread, padded p, merged
// DPP butterfly, slot-refill x4, shift update every 4th step, LDS-only
// barrier). New this round:
//  * expT kernel fused: E-frag = __expf(trans[...]) inline in the prologue
//    (trans is 64KB, L2/L3-hot across 256 blocks; 64 scalar loads + 64 expf
//    amortized under prologue latency). No workspace, no dependency.
//  * num kernel fused: per-thread gather partials (4 t-steps each) computed
//    in the prologue, carried in 2 VGPRs through the scan, reduced in the
//    epilogue sharing the den-LSE's two __syncthreads.
//  * mask quad-read: one broadcast ds_read_b128 per 4-step group, loaded one
//    body EARLY (in the previous group's last body) so the read latency is
//    hidden; replaces 4 scalar ds_read_b32 (-3 DS ops / 4 steps).
__global__ __launch_bounds__(256)
__attribute__((amdgpu_waves_per_eu(1, 1)))
void crf_fused_kernel(
    const float* __restrict__ h, const int* __restrict__ labels,
    const float* __restrict__ mask, const float* __restrict__ trans,
    const float* __restrict__ start_trans, const float* __restrict__ end_trans,
    float* __restrict__ out)
{
    __shared__ float p_lds[2][160];      // padded: addr(i) = i + (i>>4)*4
    __shared__ float mk_lds[Tt + 4];     // +4: tail MQ dummy-read stays in-bounds
    __shared__ float redm[4], reds[4], racc[4], rmsum[4];

    const int b = blockIdx.x;
    const int tid = threadIdx.x;
    const int wave = tid >> 6;
    const int lane = tid & 63;
    const int jgrp = lane >> 3;                    // 8 column-groups per wave
    const int isl  = lane & 7;                     // i-slice 0..7 (16 i each)
    const int jbase = (wave << 5) + (jgrp << 2);   // 4 columns per thread
    const int wcol  = jbase + (isl & 3);           // column this lane writes
    const bool writer = (isl < 4);
    const int waddr = wcol + ((wcol >> 4) << 2);
    const bool lb0 = (lane & 1) != 0;
    const bool lb1 = (lane & 2) != 0;

    const float* hb = h + (size_t)b * Tt * Ll;
    const float* mk = mask + b * Tt;
    const int* lab = labels + b * Tt;

    // stage mask row into LDS, vectorized (256 threads x float4 = 1024)
    ((float4*)mk_lds)[tid] = ((const float4*)mk)[tid];

    // ---- fused num partials (old crf_num_kernel body), kept in 2 VGPRs ----
    float nacc = 0.f, nms = 0.f;
    #pragma unroll
    for (int r = 0; r < 4; ++r) {
        int t = tid + (r << 8);
        float mt = mk[t];
        nms += mt;
        if (t < Tt - 1) {
            int lt = lab[t], lt1 = lab[t + 1];
            nacc += hb[t * Ll + lt] * mt + trans[lt * Ll + lt1] * mk[t + 1];
        }
    }

    // ---- E fragment inline from trans: cols jbase+0..3, i in [isl*16,+16) ----
    const float* tp = trans + (size_t)(isl << 4) * Ll + jbase;
#define EXT2(k, c) ev2(__expf(tp[(2 * (k)) * Ll + (c)]), __expf(tp[(2 * (k) + 1) * Ll + (c)]))
    v2f EA0=EXT2(0,0),EA1=EXT2(1,0),EA2=EXT2(2,0),EA3=EXT2(3,0),
        EA4=EXT2(4,0),EA5=EXT2(5,0),EA6=EXT2(6,0),EA7=EXT2(7,0);
    v2f EB0=EXT2(0,1),EB1=EXT2(1,1),EB2=EXT2(2,1),EB3=EXT2(3,1),
        EB4=EXT2(4,1),EB5=EXT2(5,1),EB6=EXT2(6,1),EB7=EXT2(7,1);
    v2f EC0=EXT2(0,2),EC1=EXT2(1,2),EC2=EXT2(2,2),EC3=EXT2(3,2),
        EC4=EXT2(4,2),EC5=EXT2(5,2),EC6=EXT2(6,2),EC7=EXT2(7,2);
    v2f ED0=EXT2(0,3),ED1=EXT2(1,3),ED2=EXT2(2,3),ED3=EXT2(3,3),
        ED4=EXT2(4,3),ED5=EXT2(5,3),ED6=EXT2(6,3),ED7=EXT2(7,3);
#undef EXT2

    // bootstrap t = 0: shift S0 = score_0[0] + 16, computed uniformly
    float S = start_trans[0] + hb[0] + 16.0f;
    float score0 = start_trans[wcol] + hb[wcol];
    float pw = __expf(score0 - S);
    if (writer) p_lds[0][waddr] = pw;

    // h/mask slots (slot r holds data for time t with t&3 == r)
    float h1 = hb[1 * Ll + wcol], m1 = mk[1];
    float h2 = hb[2 * Ll + wcol], m2 = mk[2];
    float h3 = hb[3 * Ll + wcol], m3 = mk[3];
    float h0 = hb[4 * Ll + wcol], m0 = mk[4];
    __syncthreads();

    float ex1 = __expf(h1) * m1, om1 = 1.f - m1;
    float ex0, om0, ex2, om2, ex3, om3;
    float4 MQ;   // mask quad for the next 4-step group

    // DPP cross-lane value; old=0, bound_ctrl=true
#define DPPA(x, ctrl) __int_as_float(__builtin_amdgcn_update_dpp( \
        0, __float_as_int(x), ctrl, 0xF, 0xF, true))

    // BODY: one scan step (R15 semantics). MV = this body's refill-mask value.
    // LQ = load MQ for the NEXT group from mk_lds[TR+1] (after MV consumed).
#define BODY(RBUF, UPD, EXc, OMc, HN, MN, EXn, OMn, HR, MR, TR, MV, LQ) {  \
    const float4* pp = (const float4*)(&p_lds[RBUF][isl * 20]);        \
    float4 Q0 = pp[0], Q1 = pp[1], Q2 = pp[2], Q3 = pp[3];             \
    float pz = 0.f;                                                    \
    if (UPD) pz = p_lds[RBUF][0];                                      \
    HR = hb[(TR) * Ll + wcol];                                         \
    MR = (MV);                                                         \
    if (LQ) MQ = *(const float4*)(&mk_lds[(TR) + 1]);                  \
    v2f q00 = {Q0.x,Q0.y}, q01 = {Q0.z,Q0.w};                          \
    v2f q10 = {Q1.x,Q1.y}, q11 = {Q1.z,Q1.w};                          \
    v2f q20 = {Q2.x,Q2.y}, q21 = {Q2.z,Q2.w};                          \
    v2f q30 = {Q3.x,Q3.y}, q31 = {Q3.z,Q3.w};                          \
    v2f A0 = q00*EA0; A0 = q01*EA1 + A0; A0 = q10*EA2 + A0;            \
    A0 = q11*EA3 + A0; A0 = q20*EA4 + A0; A0 = q21*EA5 + A0;           \
    A0 = q30*EA6 + A0; A0 = q31*EA7 + A0;                              \
    v2f A1 = q00*EB0; A1 = q01*EB1 + A1; A1 = q10*EB2 + A1;            \
    A1 = q11*EB3 + A1; A1 = q20*EB4 + A1; A1 = q21*EB5 + A1;           \
    A1 = q30*EB6 + A1; A1 = q31*EB7 + A1;                              \
    v2f A2 = q00*EC0; A2 = q01*EC1 + A2; A2 = q10*EC2 + A2;            \
    A2 = q11*EC3 + A2; A2 = q20*EC4 + A2; A2 = q21*EC5 + A2;           \
    A2 = q30*EC6 + A2; A2 = q31*EC7 + A2;                              \
    v2f A3 = q00*ED0; A3 = q01*ED1 + A3; A3 = q10*ED2 + A3;            \
    A3 = q11*ED3 + A3; A3 = q20*ED4 + A3; A3 = q21*ED5 + A3;           \
    A3 = q30*ED6 + A3; A3 = q31*ED7 + A3;                              \
    float a0 = A0.x + A0.y, a1 = A1.x + A1.y;                          \
    float a2 = A2.x + A2.y, a3 = A3.x + A3.y;                          \
    a0 += DPPA(a0, 0x141); a1 += DPPA(a1, 0x141);                      \
    a2 += DPPA(a2, 0x141); a3 += DPPA(a3, 0x141);                      \
    float u01 = lb0 ? a1 : a0, v01 = lb0 ? a0 : a1;                    \
    float b01 = u01 + DPPA(v01, 0xB1);                                 \
    float u23 = lb0 ? a3 : a2, v23 = lb0 ? a2 : a3;                    \
    float b23 = u23 + DPPA(v23, 0xB1);                                 \
    float uf = lb1 ? b23 : b01, vf = lb1 ? b01 : b23;                  \
    float acc = uf + DPPA(vf, 0x4E);                                   \
    float c1 = EXc, c0 = pw * OMc;                                     \
    if (UPD) { float ed = __fdividef(1.12535175e-7f, pz);              \
               c1 *= ed; c0 *= ed; S += __logf(pz) + 16.0f; }          \
    float pn = fmaf(acc, c1, c0);                                      \
    if (writer) p_lds[(RBUF) ^ 1][waddr] = pn;                         \
    EXn = __expf(HN) * MN; OMn = 1.f - MN;                             \
    pw = pn;                                                           \
    __builtin_amdgcn_sched_barrier(0);                                 \
    asm volatile("s_waitcnt lgkmcnt(0)");                              \
    __builtin_amdgcn_s_barrier();                                      \
    __builtin_amdgcn_sched_barrier(0);                                 \
}

    // pre-loop bodies: t = 1, 2, 3 (scalar mask refills; body 3 preloads MQ
    // for the k=1 group from mk_lds[8..11])
    BODY(0, 0, ex1, om1, h2, m2, ex2, om2, h1, m1, 5, mk_lds[5], 0)
    BODY(1, 0, ex2, om2, h3, m3, ex3, om3, h2, m2, 6, mk_lds[6], 0)
    BODY(0, 0, ex3, om3, h0, m0, ex0, om0, h3, m3, 7, mk_lds[7], 1)

    // main loop: k = 1..254, t = 4k (update), 4k+1..4k+3. TR <= 1023.
    // body 4 consumes MQ.w THEN preloads next group's MQ (TR+1 = 4(k+1)+4).
    for (int k = 1; k < 255; ++k) {
        int t4 = k << 2;
        BODY(1, 1, ex0, om0, h1, m1, ex1, om1, h0, m0, t4 + 4, MQ.x, 0)
        BODY(0, 0, ex1, om1, h2, m2, ex2, om2, h1, m1, t4 + 5, MQ.y, 0)
        BODY(1, 0, ex2, om2, h3, m3, ex3, om3, h2, m2, t4 + 6, MQ.z, 0)
        BODY(0, 0, ex3, om3, h0, m0, ex0, om0, h3, m3, t4 + 7, MQ.w, 1)
    }
    // tail k = 255: t = 1020..1023. Refills are dummies (never consumed);
    // k=254 body4's MQ preload read mk_lds[1024..1027] (in-bounds pad, dummy).
    BODY(1, 1, ex0, om0, h1, m1, ex1, om1, h0, m0, Tt - 4, MQ.x, 0)
    BODY(0, 0, ex1, om1, h2, m2, ex2, om2, h1, m1, Tt - 1, MQ.y, 0)
    BODY(1, 0, ex2, om2, h3, m3, ex3, om3, h2, m2, Tt - 1, MQ.z, 0)
    BODY(0, 0, ex3, om3, h0, m0, ex0, om0, h3, m3, Tt - 1, MQ.w, 0)
#undef BODY
#undef DPPA

    // ---- epilogue: den logsumexp + num reduce, sharing the two syncs ----
    float v = __logf(pw) + S + end_trans[wcol];
    float mval = writer ? v : -1e30f;
    #pragma unroll
    for (int off = 32; off; off >>= 1) {
        mval = fmaxf(mval, __shfl_xor(mval, off, 64));
        nacc += __shfl_down(nacc, off, 64);
        nms  += __shfl_down(nms,  off, 64);
    }
    if (lane == 0) { redm[wave] = mval; racc[wave] = nacc; rmsum[wave] = nms; }
    __syncthreads();
    float M = fmaxf(fmaxf(redm[0], redm[1]), fmaxf(redm[2], redm[3]));
    float e = writer ? __expf(v - M) : 0.f;
    #pragma unroll
    for (int off = 32; off; off >>= 1) e += __shfl_xor(e, off, 64);
    if (lane == 0) reds[wave] = e;
    __syncthreads();
    if (tid == 0) {
        float den = M + __logf(reds[0] + reds[1] + reds[2] + reds[3]);
        float a  = racc[0] + racc[1] + racc[2] + racc[3];
        float mm = rmsum[0] + rmsum[1] + rmsum[2] + rmsum[3];
        int last_idx = (int)(mm + 0.5f) - 1;
        if (last_idx < 0) last_idx = 0;
        if (last_idx > Tt - 1) last_idx = Tt - 1;
        int last_lab = lab[last_idx];
        float num = a + start_trans[lab[0]];
        num += hb[(Tt - 1) * Ll + last_lab] * mk_lds[Tt - 1];
        num += end_trans[last_lab];
        out[b] = num - den;
    }
}

extern "C" void kernel_launch(void* const* d_in, const int* in_sizes, int n_in,
                              void* d_out, int out_size, void* d_ws, size_t ws_size,
                              hipStream_t stream) {
    const float* h           = (const float*)d_in[0];
    const int*   labels      = (const int*)d_in[1];
    const float* mask        = (const float*)d_in[2];
    const float* trans       = (const float*)d_in[3];
    const float* start_trans = (const float*)d_in[4];
    const float* end_trans   = (const float*)d_in[5];
    float* out = (float*)d_out;

    crf_fused_kernel<<<Bb, 256, 0, stream>>>(h, labels, mask, trans,
                                             start_trans, end_trans, out);
}

// Round 17
// 238.507 us; speedup vs baseline: 1.1089x; 1.0389x over previous
//
#include <hip/hip_runtime.h>
#include <hip/hip_bf16.h>
#include <math.h>

#define Bb 256
#define Tt 1024
#define Ll 128

typedef short s8v  __attribute__((ext_vector_type(8)));
typedef float f32x4 __attribute__((ext_vector_type(4)));

__device__ __forceinline__ short f2bf(float x) {   // RNE f32 -> bf16 bits
    unsigned u = __float_as_uint(x);
    unsigned r = (u + 0x7FFFu + ((u >> 16) & 1u)) >> 16;
    return (short)r;
}
__device__ __forceinline__ float bf2f(unsigned short u) {
    return __uint_as_float(((unsigned)u) << 16);
}

// ---------------- fully fused CRF kernel (MFMA scan) ----------------
// One launch, grid 256 (1 block/batch), 256 threads (4 waves, 1 wave/SIMD).
// Scan step = 1x128 x 128x128 GEMV on the matrix core:
//   s[j] = sum_i p_bf16[i] * E_bf16[i][j],  E = exp(trans)
// mfma_f32_16x16x32_bf16, wave owns 32 cols = 2 j-tiles; K=128 = 4 chunks.
// A-trick: every lane loads the SAME p k-slice for its (lane>>4) group ->
// all 16 A-rows equal p -> every D row = s (redundant, layout-robust).
// The R8-R16 DPP butterfly + 32 pk-fma + padded p all DELETED - the MFMA
// sums K internally. p exchanged as bf16 (256B/step vs 16KB).
// bf16 error budget: E,p rel err <=0.2%; log-domain ~0.004/step -> <=4 abs
// after 1023 steps vs threshold 111. Recenter algebra EXACT (pz bf16 value
// used consistently for ed scale and S tracking).
// Kept from R16: slot-refill x4 (no in-flight rotation), 4-step recenter
// (ed = e^-16/pz via fdividef), mask quad preload, LDS-only barrier
// (sched_barrier; s_waitcnt lgkmcnt(0); s_barrier; sched_barrier),
// fused num partials + inline E from trans.
__global__ __launch_bounds__(256)
__attribute__((amdgpu_waves_per_eu(1, 1)))
void crf_fused_kernel(
    const float* __restrict__ h, const int* __restrict__ labels,
    const float* __restrict__ mask, const float* __restrict__ trans,
    const float* __restrict__ start_trans, const float* __restrict__ end_trans,
    float* __restrict__ out)
{
    __shared__ __align__(16) unsigned short pbuf[2][Ll];  // bf16 p, 256B each
    __shared__ float mk_lds[Tt + 4];
    __shared__ float redm[4], reds[4], racc[4], rmsum[4];

    const int b = blockIdx.x;
    const int tid = threadIdx.x;
    const int wave = tid >> 6;
    const int lane = tid & 63;
    const int l15 = lane & 15;
    const int l4  = lane >> 4;
    const int w32 = wave << 5;
    const bool wr16 = (lane < 16);
    const int jT0 = w32 + l15;          // this lane's tile-0 column
    const int jT1 = w32 + 16 + l15;     // tile-1 column

    const float* hb = h + (size_t)b * Tt * Ll;
    const float* mk = mask + b * Tt;
    const int* lab = labels + b * Tt;

    // stage mask row into LDS
    ((float4*)mk_lds)[tid] = ((const float4*)mk)[tid];

    // ---- fused num partials ----
    float nacc = 0.f, nms = 0.f;
    #pragma unroll
    for (int r = 0; r < 4; ++r) {
        int t = tid + (r << 8);
        float mt = mk[t];
        nms += mt;
        if (t < Tt - 1) {
            int lt = lab[t], lt1 = lab[t + 1];
            nacc += hb[t * Ll + lt] * mt + trans[lt * Ll + lt1] * mk[t + 1];
        }
    }

    // ---- B fragments: E[k][j] bf16, 2 tiles x 4 K-chunks ----
    // frag element e: B[32c + 8*l4 + e][jT]; trans is L2/L3-hot (64KB shared).
#define MKB(c, J) ({ const float* tb = trans + (size_t)((c) * 32 + l4 * 8) * Ll + (J); \
    s8v r_; r_[0]=f2bf(__expf(tb[0]));      r_[1]=f2bf(__expf(tb[Ll]));     \
            r_[2]=f2bf(__expf(tb[2*Ll]));   r_[3]=f2bf(__expf(tb[3*Ll]));   \
            r_[4]=f2bf(__expf(tb[4*Ll]));   r_[5]=f2bf(__expf(tb[5*Ll]));   \
            r_[6]=f2bf(__expf(tb[6*Ll]));   r_[7]=f2bf(__expf(tb[7*Ll])); r_; })
    s8v B00 = MKB(0, jT0), B01 = MKB(1, jT0), B02 = MKB(2, jT0), B03 = MKB(3, jT0);
    s8v B10 = MKB(0, jT1), B11 = MKB(1, jT1), B12 = MKB(2, jT1), B13 = MKB(3, jT1);
#undef MKB

    // bootstrap t = 0: shift S0 = score_0[0] + 16 (uniform)
    float S = start_trans[0] + hb[0] + 16.0f;
    if (tid < Ll) {
        float sc0 = start_trans[tid] + hb[tid];
        pbuf[0][tid] = (unsigned short)f2bf(__expf(sc0 - S));
    }
    float pwA = __expf(start_trans[jT0] + hb[jT0] - S);
    float pwB = __expf(start_trans[jT1] + hb[jT1] - S);

    // h/mask slots (slot r holds data for time t with t&3 == r)
    float h1a = hb[1 * Ll + jT0], h1b = hb[1 * Ll + jT1], m1 = mk[1];
    float h2a = hb[2 * Ll + jT0], h2b = hb[2 * Ll + jT1], m2 = mk[2];
    float h3a = hb[3 * Ll + jT0], h3b = hb[3 * Ll + jT1], m3 = mk[3];
    float h0a = hb[4 * Ll + jT0], h0b = hb[4 * Ll + jT1], m0 = mk[4];
    __syncthreads();

    float ex1a = __expf(h1a) * m1, ex1b = __expf(h1b) * m1, om1 = 1.f - m1;
    float ex0a, ex0b, om0, ex2a, ex2b, om2, ex3a, ex3b, om3;
    float4 MQ;
    const f32x4 Zac = {0.f, 0.f, 0.f, 0.f};

    // BODY: one scan step. A chunks are broadcast reads (16-lane groups share
    // addresses); every A-row = p so all D rows = s (lane-robust).
#define BODY(RBUF, UPD, EXcA, EXcB, OMc, HNa, HNb, MN, EXnA, EXnB, OMn,  \
             HRa, HRb, MR, TR, MV, LQ) {                                 \
    const unsigned short* pb_ = pbuf[RBUF];                              \
    s8v a0 = *(const s8v*)(pb_ + l4 * 8);                                \
    s8v a1 = *(const s8v*)(pb_ + 32 + l4 * 8);                           \
    s8v a2 = *(const s8v*)(pb_ + 64 + l4 * 8);                           \
    s8v a3 = *(const s8v*)(pb_ + 96 + l4 * 8);                           \
    float pz = 0.f;                                                      \
    if (UPD) pz = bf2f(pb_[0]);                                          \
    HRa = hb[(TR) * Ll + jT0];                                           \
    HRb = hb[(TR) * Ll + jT1];                                           \
    MR = (MV);                                                           \
    if (LQ) MQ = *(const float4*)(&mk_lds[(TR) + 1]);                    \
    f32x4 ac0 = __builtin_amdgcn_mfma_f32_16x16x32_bf16(a0, B00, Zac, 0, 0, 0); \
    ac0 = __builtin_amdgcn_mfma_f32_16x16x32_bf16(a1, B01, ac0, 0, 0, 0);\
    ac0 = __builtin_amdgcn_mfma_f32_16x16x32_bf16(a2, B02, ac0, 0, 0, 0);\
    ac0 = __builtin_amdgcn_mfma_f32_16x16x32_bf16(a3, B03, ac0, 0, 0, 0);\
    f32x4 ac1 = __builtin_amdgcn_mfma_f32_16x16x32_bf16(a0, B10, Zac, 0, 0, 0); \
    ac1 = __builtin_amdgcn_mfma_f32_16x16x32_bf16(a1, B11, ac1, 0, 0, 0);\
    ac1 = __builtin_amdgcn_mfma_f32_16x16x32_bf16(a2, B12, ac1, 0, 0, 0);\
    ac1 = __builtin_amdgcn_mfma_f32_16x16x32_bf16(a3, B13, ac1, 0, 0, 0);\
    float s0 = ac0[0], s1 = ac1[0];                                      \
    float c1a = EXcA, c1b = EXcB;                                        \
    float c0a = pwA * OMc, c0b = pwB * OMc;                              \
    if (UPD) { float ed = __fdividef(1.12535175e-7f, pz);                \
               c1a *= ed; c1b *= ed; c0a *= ed; c0b *= ed;               \
               S += __logf(pz) + 16.0f; }                                \
    float pnA = fmaf(s0, c1a, c0a);                                      \
    float pnB = fmaf(s1, c1b, c0b);                                      \
    if (wr16) { pbuf[(RBUF) ^ 1][w32 + l15]      = (unsigned short)f2bf(pnA); \
                pbuf[(RBUF) ^ 1][w32 + 16 + l15] = (unsigned short)f2bf(pnB); } \
    EXnA = __expf(HNa) * MN; EXnB = __expf(HNb) * MN; OMn = 1.f - MN;    \
    pwA = pnA; pwB = pnB;                                                \
    __builtin_amdgcn_sched_barrier(0);                                   \
    asm volatile("s_waitcnt lgkmcnt(0)");                                \
    __builtin_amdgcn_s_barrier();                                        \
    __builtin_amdgcn_sched_barrier(0);                                   \
}

    // pre-loop bodies: t = 1, 2, 3
    BODY(0, 0, ex1a, ex1b, om1, h2a, h2b, m2, ex2a, ex2b, om2, h1a, h1b, m1, 5, mk_lds[5], 0)
    BODY(1, 0, ex2a, ex2b, om2, h3a, h3b, m3, ex3a, ex3b, om3, h2a, h2b, m2, 6, mk_lds[6], 0)
    BODY(0, 0, ex3a, ex3b, om3, h0a, h0b, m0, ex0a, ex0b, om0, h3a, h3b, m3, 7, mk_lds[7], 1)

    // main loop: k = 1..254, t = 4k (recenter), 4k+1..4k+3
    for (int k = 1; k < 255; ++k) {
        int t4 = k << 2;
        BODY(1, 1, ex0a, ex0b, om0, h1a, h1b, m1, ex1a, ex1b, om1, h0a, h0b, m0, t4 + 4, MQ.x, 0)
        BODY(0, 0, ex1a, ex1b, om1, h2a, h2b, m2, ex2a, ex2b, om2, h1a, h1b, m1, t4 + 5, MQ.y, 0)
        BODY(1, 0, ex2a, ex2b, om2, h3a, h3b, m3, ex3a, ex3b, om3, h2a, h2b, m2, t4 + 6, MQ.z, 0)
        BODY(0, 0, ex3a, ex3b, om3, h0a, h0b, m0, ex0a, ex0b, om0, h3a, h3b, m3, t4 + 7, MQ.w, 1)
    }
    // tail k = 255: t = 1020..1023 (refills dummy)
    BODY(1, 1, ex0a, ex0b, om0, h1a, h1b, m1, ex1a, ex1b, om1, h0a, h0b, m0, Tt - 1, MQ.x, 0)
    BODY(0, 0, ex1a, ex1b, om1, h2a, h2b, m2, ex2a, ex2b, om2, h1a, h1b, m1, Tt - 1, MQ.y, 0)
    BODY(1, 0, ex2a, ex2b, om2, h3a, h3b, m3, ex3a, ex3b, om3, h2a, h2b, m2, Tt - 1, MQ.z, 0)
    BODY(0, 0, ex3a, ex3b, om3, h0a, h0b, m0, ex0a, ex0b, om0, h3a, h3b, m3, Tt - 1, MQ.w, 0)
#undef BODY

    // ---- epilogue: den logsumexp + num reduce ----
    float v0 = __logf(pwA) + S + end_trans[jT0];
    float v1 = __logf(pwB) + S + end_trans[jT1];
    float mval = wr16 ? fmaxf(v0, v1) : -1e30f;
    #pragma unroll
    for (int off = 32; off; off >>= 1) {
        mval = fmaxf(mval, __shfl_xor(mval, off, 64));
        nacc += __shfl_down(nacc, off, 64);
        nms  += __shfl_down(nms,  off, 64);
    }
    if (lane == 0) { redm[wave] = mval; racc[wave] = nacc; rmsum[wave] = nms; }
    __syncthreads();
    float M = fmaxf(fmaxf(redm[0], redm[1]), fmaxf(redm[2], redm[3]));
    float e = wr16 ? (__expf(v0 - M) + __expf(v1 - M)) : 0.f;
    #pragma unroll
    for (int off = 32; off; off >>= 1) e += __shfl_xor(e, off, 64);
    if (lane == 0) reds[wave] = e;
    __syncthreads();
    if (tid == 0) {
        float den = M + __logf(reds[0] + reds[1] + reds[2] + reds[3]);
        float a  = racc[0] + racc[1] + racc[2] + racc[3];
        float mm = rmsum[0] + rmsum[1] + rmsum[2] + rmsum[3];
        int last_idx = (int)(mm + 0.5f) - 1;
        if (last_idx < 0) last_idx = 0;
        if (last_idx > Tt - 1) last_idx = Tt - 1;
        int last_lab = lab[last_idx];
        float num = a + start_trans[lab[0]];
        num += hb[(Tt - 1) * Ll + last_lab] * mk_lds[Tt - 1];
        num += end_trans[last_lab];
        out[b] = num - den;
    }
}

extern "C" void kernel_launch(void* const* d_in, const int* in_sizes, int n_in,
                              void* d_out, int out_size, void* d_ws, size_t ws_size,
                              hipStream_t stream) {
    const float* h           = (const float*)d_in[0];
    const int*   labels      = (const int*)d_in[1];
    const float* mask        = (const float*)d_in[2];
    const float* trans       = (const float*)d_in[3];
    const float* start_trans = (const float*)d_in[4];
    const float* end_trans   = (const float*)d_in[5];
    float* out = (float*)d_out;

    crf_fused_kernel<<<Bb, 256, 0, stream>>>(h, labels, mask, trans,
                                             start_trans, end_trans, out);
}